// Round 1
// baseline (825.616 us; speedup 1.0000x reference)
//
#include <hip/hip_runtime.h>

#define NB 512
#define NN 200
#define ND 256
#define TI 40
#define DC 32
#define NTILE 5            // NN / TI
#define NEG_INF -9.0e15f
#define SLOPE 0.2f

#define HJ_STRIDE 205      // odd-ish stride: conflict-free reads, ~2-way writes
#define HI_STRIDE 45

__global__ __launch_bounds__(512, 4)
void gat_fused_kernel(const float* __restrict__ h,
                      const int*   __restrict__ adj,
                      const float* __restrict__ a0,
                      const float* __restrict__ a1,
                      const float* __restrict__ a2,
                      const float* __restrict__ a3,
                      float* __restrict__ out)
{
    __shared__ float sHjT[DC][HJ_STRIDE];   // transposed h_j chunk: [d][j]
    __shared__ float sHiT[DC][HI_STRIDE];   // transposed h_i chunk: [d][i_local]
    __shared__ float sA[4][ND];             // a0..a3
    __shared__ float sS[TI][NN];            // scores -> alpha (in place)

    const int tid = threadIdx.x;
    const int b   = blockIdx.x / NTILE;
    const int it  = blockIdx.x % NTILE;
    const int i0  = it * TI;

    // ---- stage a0..a3 into LDS (once) ----
    for (int idx = tid; idx < 4 * ND; idx += 512) {
        const int k = idx >> 8;
        const int d = idx & (ND - 1);
        const float* ap = (k == 0) ? a0 : (k == 1) ? a1 : (k == 2) ? a2 : a3;
        sA[k][d] = ap[d];
    }

    // ---- score-phase thread mapping: 10 i-groups x 50 j-groups (500 active) ----
    const int ig = tid / 50;            // 0..10 (10 => inactive)
    const int jg = tid % 50;
    const bool active = (ig < 10);

    const float* hb = h + (size_t)b * NN * ND;

    // read adj selections once; k = adj-1 in [0,3], -1 => masked
    int kk[4][4];
    if (active) {
        #pragma unroll
        for (int ii = 0; ii < 4; ++ii) {
            const int i = i0 + ig * 4 + ii;
            const int* arow = adj + ((size_t)b * NN + i) * NN;
            #pragma unroll
            for (int jj = 0; jj < 4; ++jj)
                kk[ii][jj] = arow[jg + 50 * jj] - 1;
        }
    }

    // 4x4 pair tile, 4 k-accumulators each (selection deferred past the d-loop)
    float acc[4][4][4];
    #pragma unroll
    for (int ii = 0; ii < 4; ++ii)
        #pragma unroll
        for (int jj = 0; jj < 4; ++jj)
            #pragma unroll
            for (int k = 0; k < 4; ++k)
                acc[ii][jj][k] = 0.0f;

    // ---- score phase: loop d in chunks of DC ----
    for (int dt = 0; dt < ND; dt += DC) {
        // stage h_j[0..199][dt..dt+31] and h_i tile, transposed
        {
            const int row = tid >> 3;            // 0..63
            const int c4  = (tid & 7) * 4;       // 0,4,...,28
            for (int j = row; j < NN; j += 64) {
                const float4 v = *(const float4*)(hb + j * ND + dt + c4);
                sHjT[c4 + 0][j] = v.x;
                sHjT[c4 + 1][j] = v.y;
                sHjT[c4 + 2][j] = v.z;
                sHjT[c4 + 3][j] = v.w;
            }
            for (int r = row; r < TI; r += 64) {
                const float4 v = *(const float4*)(hb + (i0 + r) * ND + dt + c4);
                sHiT[c4 + 0][r] = v.x;
                sHiT[c4 + 1][r] = v.y;
                sHiT[c4 + 2][r] = v.z;
                sHiT[c4 + 3][r] = v.w;
            }
        }
        __syncthreads();

        if (active) {
            #pragma unroll 4
            for (int dd = 0; dd < DC; ++dd) {
                const float av0 = sA[0][dt + dd];   // uniform-address broadcasts
                const float av1 = sA[1][dt + dd];
                const float av2 = sA[2][dt + dd];
                const float av3 = sA[3][dt + dd];
                float hiv[4], hjv[4];
                #pragma unroll
                for (int ii = 0; ii < 4; ++ii) hiv[ii] = sHiT[dd][ig * 4 + ii];
                #pragma unroll
                for (int jj = 0; jj < 4; ++jj) hjv[jj] = sHjT[dd][jg + 50 * jj];
                #pragma unroll
                for (int ii = 0; ii < 4; ++ii) {
                    #pragma unroll
                    for (int jj = 0; jj < 4; ++jj) {
                        const float t = hiv[ii] * hjv[jj];
                        acc[ii][jj][0] += t * av0;
                        acc[ii][jj][1] += t * av1;
                        acc[ii][jj][2] += t * av2;
                        acc[ii][jj][3] += t * av3;
                    }
                }
            }
        }
        __syncthreads();
    }

    // ---- select k, leaky-relu, mask, write scores to LDS ----
    if (active) {
        #pragma unroll
        for (int ii = 0; ii < 4; ++ii) {
            #pragma unroll
            for (int jj = 0; jj < 4; ++jj) {
                const int k = kk[ii][jj];
                float s = (k < 2) ? ((k == 0) ? acc[ii][jj][0] : acc[ii][jj][1])
                                  : ((k == 2) ? acc[ii][jj][2] : acc[ii][jj][3]);
                s = (s >= 0.0f) ? s : SLOPE * s;
                s = (k >= 0) ? s : NEG_INF;
                sS[ig * 4 + ii][jg + 50 * jj] = s;
            }
        }
    }
    __syncthreads();

    // ---- row softmax: 8 waves x 5 rows, shuffle reduce over 64 lanes ----
    const int wv   = tid >> 6;   // 0..7
    const int lane = tid & 63;
    #pragma unroll
    for (int r = 0; r < 5; ++r) {
        const int row = wv * 5 + r;
        const float v0 = sS[row][lane];
        const float v1 = sS[row][lane + 64];
        const float v2 = sS[row][lane + 128];
        const float v3 = (lane < 8) ? sS[row][lane + 192] : NEG_INF;
        float m = fmaxf(fmaxf(v0, v1), fmaxf(v2, v3));
        #pragma unroll
        for (int off = 32; off > 0; off >>= 1)
            m = fmaxf(m, __shfl_xor(m, off, 64));
        const float p0 = __expf(v0 - m);
        const float p1 = __expf(v1 - m);
        const float p2 = __expf(v2 - m);
        const float p3 = (lane < 8) ? __expf(v3 - m) : 0.0f;
        float l = p0 + p1 + p2 + p3;
        #pragma unroll
        for (int off = 32; off > 0; off >>= 1)
            l += __shfl_xor(l, off, 64);
        const float inv = 1.0f / l;
        sS[row][lane]       = p0 * inv;
        sS[row][lane + 64]  = p1 * inv;
        sS[row][lane + 128] = p2 * inv;
        if (lane < 8) sS[row][lane + 192] = p3 * inv;
    }
    __syncthreads();

    // ---- PV: out[i][:] = sum_j alpha[i][j] * h[j][:]  (wave = 5 rows) ----
    float o[5][4];
    #pragma unroll
    for (int r = 0; r < 5; ++r)
        #pragma unroll
        for (int c = 0; c < 4; ++c)
            o[r][c] = 0.0f;

    const int dcol = lane * 4;
    #pragma unroll 4
    for (int j = 0; j < NN; ++j) {
        const float4 hv = *(const float4*)(hb + j * ND + dcol);
        #pragma unroll
        for (int r = 0; r < 5; ++r) {
            const float al = sS[wv * 5 + r][j];   // uniform-address broadcast
            o[r][0] += al * hv.x;
            o[r][1] += al * hv.y;
            o[r][2] += al * hv.z;
            o[r][3] += al * hv.w;
        }
    }

    #pragma unroll
    for (int r = 0; r < 5; ++r) {
        const int i = i0 + wv * 5 + r;
        float4 v;
        v.x = o[r][0]; v.y = o[r][1]; v.z = o[r][2]; v.w = o[r][3];
        *(float4*)(out + ((size_t)b * NN + i) * ND + dcol) = v;
    }
}

extern "C" void kernel_launch(void* const* d_in, const int* in_sizes, int n_in,
                              void* d_out, int out_size, void* d_ws, size_t ws_size,
                              hipStream_t stream) {
    const float* h   = (const float*)d_in[0];
    const int*   adj = (const int*)d_in[1];
    const float* a0  = (const float*)d_in[2];
    const float* a1  = (const float*)d_in[3];
    const float* a2  = (const float*)d_in[4];
    const float* a3  = (const float*)d_in[5];
    float* out = (float*)d_out;

    dim3 grid(NB * NTILE);   // 2560 blocks
    dim3 block(512);
    gat_fused_kernel<<<grid, block, 0, stream>>>(h, adj, a0, a1, a2, a3, out);
}

// Round 5
// 730.137 us; speedup vs baseline: 1.1308x; 1.1308x over previous
//
#include <hip/hip_runtime.h>

#define NB 512
#define NN 200
#define ND 256
#define TI 40
#define DC 32
#define NTILE 5            // NN / TI
#define NEG_INF -9.0e15f
#define SLOPE 0.2f

#define HJ_STRIDE 205      // conflict-free consecutive-lane reads
#define WI_STRIDE 44       // w-plane stride (broadcast reads, ~2-way writes)

__global__ __launch_bounds__(512, 4)
void gat_fused_w_kernel(const float* __restrict__ h,
                        const int*   __restrict__ adj,
                        const float* __restrict__ a0,
                        const float* __restrict__ a1,
                        const float* __restrict__ a2,
                        const float* __restrict__ a3,
                        float* __restrict__ out)
{
    __shared__ float sHjT[DC][HJ_STRIDE];      // transposed h_j chunk: [d][j]      26240 B
    __shared__ float sW[4][DC][WI_STRIDE];     // w_k = h_i*a_k, transposed [k][d][i] 22528 B
    __shared__ float sS[TI][NN];               // scores -> alpha (in place)         32000 B

    const int tid = threadIdx.x;
    const int b   = blockIdx.x / NTILE;
    const int it  = blockIdx.x % NTILE;
    const int i0  = it * TI;

    // ---- score-phase thread mapping: 10 i-groups x 50 j-groups (500 active) ----
    const int ig = tid / 50;            // 0..10 (10 => inactive)
    const int jg = tid % 50;
    const bool active = (ig < 10);

    const float* hb = h + (size_t)b * NN * ND;

    // read adj selections once; k = adj-1 in [0,3], -1 => masked
    int kk[4][4];
    if (active) {
        #pragma unroll
        for (int ii = 0; ii < 4; ++ii) {
            const int i = i0 + ig * 4 + ii;
            const int* arow = adj + ((size_t)b * NN + i) * NN;
            #pragma unroll
            for (int jj = 0; jj < 4; ++jj)
                kk[ii][jj] = arow[jg + 50 * jj] - 1;
        }
    }

    // 4x4 pair tile, 4 k-accumulators each (selection deferred past the d-loop)
    float acc[4][4][4];
    #pragma unroll
    for (int ii = 0; ii < 4; ++ii)
        #pragma unroll
        for (int jj = 0; jj < 4; ++jj)
            #pragma unroll
            for (int k = 0; k < 4; ++k)
                acc[ii][jj][k] = 0.0f;

    // ---- score phase: loop d in chunks of DC ----
    for (int dt = 0; dt < ND; dt += DC) {
        // stage h_j[0..199][dt..dt+31] transposed, and w_k = h_i*a_k transposed
        {
            const int row = tid >> 3;            // 0..63
            const int c4  = (tid & 7) * 4;       // 0,4,...,28
            for (int j = row; j < NN; j += 64) {
                const float4 v = *(const float4*)(hb + j * ND + dt + c4);
                sHjT[c4 + 0][j] = v.x;
                sHjT[c4 + 1][j] = v.y;
                sHjT[c4 + 2][j] = v.z;
                sHjT[c4 + 3][j] = v.w;
            }
            for (int r = row; r < TI; r += 64) {   // trips at most once (row<40)
                const float4 hv  = *(const float4*)(hb + (i0 + r) * ND + dt + c4);
                const float4 va0 = *(const float4*)(a0 + dt + c4);
                const float4 va1 = *(const float4*)(a1 + dt + c4);
                const float4 va2 = *(const float4*)(a2 + dt + c4);
                const float4 va3 = *(const float4*)(a3 + dt + c4);
                sW[0][c4 + 0][r] = hv.x * va0.x;
                sW[0][c4 + 1][r] = hv.y * va0.y;
                sW[0][c4 + 2][r] = hv.z * va0.z;
                sW[0][c4 + 3][r] = hv.w * va0.w;
                sW[1][c4 + 0][r] = hv.x * va1.x;
                sW[1][c4 + 1][r] = hv.y * va1.y;
                sW[1][c4 + 2][r] = hv.z * va1.z;
                sW[1][c4 + 3][r] = hv.w * va1.w;
                sW[2][c4 + 0][r] = hv.x * va2.x;
                sW[2][c4 + 1][r] = hv.y * va2.y;
                sW[2][c4 + 2][r] = hv.z * va2.z;
                sW[2][c4 + 3][r] = hv.w * va2.w;
                sW[3][c4 + 0][r] = hv.x * va3.x;
                sW[3][c4 + 1][r] = hv.y * va3.y;
                sW[3][c4 + 2][r] = hv.z * va3.z;
                sW[3][c4 + 3][r] = hv.w * va3.w;
            }
        }
        __syncthreads();

        if (active) {
            #pragma unroll 4
            for (int dd = 0; dd < DC; ++dd) {
                float hjv[4];
                #pragma unroll
                for (int jj = 0; jj < 4; ++jj) hjv[jj] = sHjT[dd][jg + 50 * jj];
                #pragma unroll
                for (int k = 0; k < 4; ++k) {
                    float wv_[4];
                    #pragma unroll
                    for (int ii = 0; ii < 4; ++ii) wv_[ii] = sW[k][dd][ig * 4 + ii];
                    #pragma unroll
                    for (int ii = 0; ii < 4; ++ii)
                        #pragma unroll
                        for (int jj = 0; jj < 4; ++jj)
                            acc[ii][jj][k] += wv_[ii] * hjv[jj];
                }
            }
        }
        __syncthreads();
    }

    // ---- select k, leaky-relu, mask, write scores to LDS ----
    if (active) {
        #pragma unroll
        for (int ii = 0; ii < 4; ++ii) {
            #pragma unroll
            for (int jj = 0; jj < 4; ++jj) {
                const int k = kk[ii][jj];
                float s = (k < 2) ? ((k == 0) ? acc[ii][jj][0] : acc[ii][jj][1])
                                  : ((k == 2) ? acc[ii][jj][2] : acc[ii][jj][3]);
                s = (s >= 0.0f) ? s : SLOPE * s;
                s = (k >= 0) ? s : NEG_INF;
                sS[ig * 4 + ii][jg + 50 * jj] = s;
            }
        }
    }
    __syncthreads();

    // ---- row softmax: 8 waves x 5 rows, shuffle reduce over 64 lanes ----
    const int wv   = tid >> 6;   // 0..7
    const int lane = tid & 63;
    #pragma unroll
    for (int r = 0; r < 5; ++r) {
        const int row = wv * 5 + r;
        const float v0 = sS[row][lane];
        const float v1 = sS[row][lane + 64];
        const float v2 = sS[row][lane + 128];
        const float v3 = (lane < 8) ? sS[row][lane + 192] : NEG_INF;
        float m = fmaxf(fmaxf(v0, v1), fmaxf(v2, v3));
        #pragma unroll
        for (int off = 32; off > 0; off >>= 1)
            m = fmaxf(m, __shfl_xor(m, off, 64));
        const float p0 = __expf(v0 - m);
        const float p1 = __expf(v1 - m);
        const float p2 = __expf(v2 - m);
        const float p3 = (lane < 8) ? __expf(v3 - m) : 0.0f;
        float l = p0 + p1 + p2 + p3;
        #pragma unroll
        for (int off = 32; off > 0; off >>= 1)
            l += __shfl_xor(l, off, 64);
        const float inv = 1.0f / l;
        sS[row][lane]       = p0 * inv;
        sS[row][lane + 64]  = p1 * inv;
        sS[row][lane + 128] = p2 * inv;
        if (lane < 8) sS[row][lane + 192] = p3 * inv;
    }
    __syncthreads();

    // ---- PV: out[i][:] = sum_j alpha[i][j] * h[j][:]  (wave = 5 rows) ----
    float o[5][4];
    #pragma unroll
    for (int r = 0; r < 5; ++r)
        #pragma unroll
        for (int c = 0; c < 4; ++c)
            o[r][c] = 0.0f;

    const int dcol = lane * 4;
    #pragma unroll 4
    for (int j = 0; j < NN; ++j) {
        const float4 hv = *(const float4*)(hb + j * ND + dcol);
        #pragma unroll
        for (int r = 0; r < 5; ++r) {
            const float al = sS[wv * 5 + r][j];   // uniform-address broadcast
            o[r][0] += al * hv.x;
            o[r][1] += al * hv.y;
            o[r][2] += al * hv.z;
            o[r][3] += al * hv.w;
        }
    }

    #pragma unroll
    for (int r = 0; r < 5; ++r) {
        const int i = i0 + wv * 5 + r;
        float4 v;
        v.x = o[r][0]; v.y = o[r][1]; v.z = o[r][2]; v.w = o[r][3];
        *(float4*)(out + ((size_t)b * NN + i) * ND + dcol) = v;
    }
}

extern "C" void kernel_launch(void* const* d_in, const int* in_sizes, int n_in,
                              void* d_out, int out_size, void* d_ws, size_t ws_size,
                              hipStream_t stream) {
    const float* h   = (const float*)d_in[0];
    const int*   adj = (const int*)d_in[1];
    const float* a0  = (const float*)d_in[2];
    const float* a1  = (const float*)d_in[3];
    const float* a2  = (const float*)d_in[4];
    const float* a3  = (const float*)d_in[5];
    float* out = (float*)d_out;

    dim3 grid(NB * NTILE);   // 2560 blocks
    dim3 block(512);
    gat_fused_w_kernel<<<grid, block, 0, stream>>>(h, adj, a0, a1, a2, a3, out);
}

// Round 6
// 651.012 us; speedup vs baseline: 1.2682x; 1.1215x over previous
//
#include <hip/hip_runtime.h>

#define NB 512
#define NN 200
#define ND 256
#define TI 40
#define DC 32
#define NTILE 5            // NN / TI
#define NEG_INF -9.0e15f
#define SLOPE 0.2f

#define HJ_STRIDE 204      // floats; 816B rows (16B-aligned), bank-spread reads
#define WI_STRIDE 44       // floats; 176B rows (16B-aligned)
#define P1_HJ (DC * HJ_STRIDE)          // 6528 floats
#define P1_W  (4 * DC * WI_STRIDE)      // 5632 floats
#define POOLF (P1_HJ + P1_W)            // 12160 floats = 48640 B (>= sS 8000 floats)

__global__ __launch_bounds__(512, 4)
void gat_fused_w2_kernel(const float* __restrict__ h,
                         const int*   __restrict__ adj,
                         const float* __restrict__ a0,
                         const float* __restrict__ a1,
                         const float* __restrict__ a2,
                         const float* __restrict__ a3,
                         float* __restrict__ out)
{
    // One all-float pool; phase-1 (sHjT,sW) and phase-2 (sS) lifetimes are
    // disjoint (barrier-separated). No mixed-type punning anywhere.
    __shared__ __align__(16) float pool[POOLF];
    float (*sHjT)[HJ_STRIDE]   = (float (*)[HJ_STRIDE])pool;             // [DC][204]
    float (*sW)[DC][WI_STRIDE] = (float (*)[DC][WI_STRIDE])(pool + P1_HJ); // [4][DC][44]
    float (*sS)[NN]            = (float (*)[NN])pool;                    // [TI][200]

    const int tid = threadIdx.x;
    const int b   = blockIdx.x / NTILE;
    const int it  = blockIdx.x % NTILE;
    const int i0  = it * TI;

    // ---- score-phase mapping: 10 i-groups x 50 j-quads (500 active) ----
    const int ig = tid / 50;            // 0..10 (10 => inactive)
    const int jg = tid % 50;            // j-quad index: j = 4*jg + jj
    const bool active = (ig < 10);

    const float* hb = h + (size_t)b * NN * ND;

    // read adj selections once (vector int4); k = adj-1 in [0,3], -1 => masked
    int kk[4][4];
    if (active) {
        #pragma unroll
        for (int ii = 0; ii < 4; ++ii) {
            const int i = i0 + ig * 4 + ii;
            const int4 a4 = *(const int4*)(adj + ((size_t)b * NN + i) * NN + 4 * jg);
            kk[ii][0] = a4.x - 1;
            kk[ii][1] = a4.y - 1;
            kk[ii][2] = a4.z - 1;
            kk[ii][3] = a4.w - 1;
        }
    }

    // 4x4 pair tile, 4 k-accumulators each (selection deferred past the d-loop)
    float acc[4][4][4];
    #pragma unroll
    for (int ii = 0; ii < 4; ++ii)
        #pragma unroll
        for (int jj = 0; jj < 4; ++jj)
            #pragma unroll
            for (int k = 0; k < 4; ++k)
                acc[ii][jj][k] = 0.0f;

    // ---- score phase: loop d in chunks of DC ----
    for (int dt = 0; dt < ND; dt += DC) {
        // stage h_j transposed, and w_k = h_i*a_k transposed
        {
            const int row = tid >> 3;            // 0..63
            const int c4  = (tid & 7) * 4;       // 0,4,...,28
            for (int j = row; j < NN; j += 64) {
                const float4 v = *(const float4*)(hb + j * ND + dt + c4);
                sHjT[c4 + 0][j] = v.x;
                sHjT[c4 + 1][j] = v.y;
                sHjT[c4 + 2][j] = v.z;
                sHjT[c4 + 3][j] = v.w;
            }
            for (int r = row; r < TI; r += 64) {   // trips at most once
                const float4 hv  = *(const float4*)(hb + (i0 + r) * ND + dt + c4);
                const float4 va0 = *(const float4*)(a0 + dt + c4);
                const float4 va1 = *(const float4*)(a1 + dt + c4);
                const float4 va2 = *(const float4*)(a2 + dt + c4);
                const float4 va3 = *(const float4*)(a3 + dt + c4);
                sW[0][c4 + 0][r] = hv.x * va0.x;
                sW[0][c4 + 1][r] = hv.y * va0.y;
                sW[0][c4 + 2][r] = hv.z * va0.z;
                sW[0][c4 + 3][r] = hv.w * va0.w;
                sW[1][c4 + 0][r] = hv.x * va1.x;
                sW[1][c4 + 1][r] = hv.y * va1.y;
                sW[1][c4 + 2][r] = hv.z * va1.z;
                sW[1][c4 + 3][r] = hv.w * va1.w;
                sW[2][c4 + 0][r] = hv.x * va2.x;
                sW[2][c4 + 1][r] = hv.y * va2.y;
                sW[2][c4 + 2][r] = hv.z * va2.z;
                sW[2][c4 + 3][r] = hv.w * va2.w;
                sW[3][c4 + 0][r] = hv.x * va3.x;
                sW[3][c4 + 1][r] = hv.y * va3.y;
                sW[3][c4 + 2][r] = hv.z * va3.z;
                sW[3][c4 + 3][r] = hv.w * va3.w;
            }
        }
        __syncthreads();

        if (active) {
            #pragma unroll 4
            for (int dd = 0; dd < DC; ++dd) {
                const float4 hj4 = *(const float4*)&sHjT[dd][4 * jg];   // 1 b128
                const float hjv[4] = {hj4.x, hj4.y, hj4.z, hj4.w};
                #pragma unroll
                for (int k = 0; k < 4; ++k) {
                    const float4 w4 = *(const float4*)&sW[k][dd][4 * ig]; // 1 b128 (2-way bcast)
                    const float wv_[4] = {w4.x, w4.y, w4.z, w4.w};
                    #pragma unroll
                    for (int ii = 0; ii < 4; ++ii)
                        #pragma unroll
                        for (int jj = 0; jj < 4; ++jj)
                            acc[ii][jj][k] += wv_[ii] * hjv[jj];
                }
            }
        }
        __syncthreads();
    }
    // phase-1 LDS dead from here; sS takes over the pool (barrier above).

    // ---- select k, leaky-relu, mask, write scores to LDS (float4) ----
    if (active) {
        #pragma unroll
        for (int ii = 0; ii < 4; ++ii) {
            float tmp[4];
            #pragma unroll
            for (int jj = 0; jj < 4; ++jj) {
                const int k = kk[ii][jj];
                float s = (k < 2) ? ((k == 0) ? acc[ii][jj][0] : acc[ii][jj][1])
                                  : ((k == 2) ? acc[ii][jj][2] : acc[ii][jj][3]);
                s = (s >= 0.0f) ? s : SLOPE * s;
                tmp[jj] = (k >= 0) ? s : NEG_INF;
            }
            float4 sv;
            sv.x = tmp[0]; sv.y = tmp[1]; sv.z = tmp[2]; sv.w = tmp[3];
            *(float4*)&sS[ig * 4 + ii][4 * jg] = sv;
        }
    }
    __syncthreads();

    // ---- row softmax: 8 waves x 5 rows, shuffle reduce over 64 lanes ----
    const int wv   = tid >> 6;   // 0..7
    const int lane = tid & 63;
    #pragma unroll
    for (int r = 0; r < 5; ++r) {
        const int row = wv * 5 + r;
        const float v0 = sS[row][lane];
        const float v1 = sS[row][lane + 64];
        const float v2 = sS[row][lane + 128];
        const float v3 = (lane < 8) ? sS[row][lane + 192] : NEG_INF;
        float m = fmaxf(fmaxf(v0, v1), fmaxf(v2, v3));
        #pragma unroll
        for (int off = 32; off > 0; off >>= 1)
            m = fmaxf(m, __shfl_xor(m, off, 64));
        const float p0 = __expf(v0 - m);
        const float p1 = __expf(v1 - m);
        const float p2 = __expf(v2 - m);
        const float p3 = (lane < 8) ? __expf(v3 - m) : 0.0f;
        float l = p0 + p1 + p2 + p3;
        #pragma unroll
        for (int off = 32; off > 0; off >>= 1)
            l += __shfl_xor(l, off, 64);
        const float inv = 1.0f / l;
        sS[row][lane]       = p0 * inv;
        sS[row][lane + 64]  = p1 * inv;
        sS[row][lane + 128] = p2 * inv;
        if (lane < 8) sS[row][lane + 192] = p3 * inv;
    }
    __syncthreads();

    // ---- PV: out[i][:] = sum_j alpha[i][j] * h[j][:]  (wave = 5 rows, j-quads) ----
    float o[5][4];
    #pragma unroll
    for (int r = 0; r < 5; ++r)
        #pragma unroll
        for (int c = 0; c < 4; ++c)
            o[r][c] = 0.0f;

    const int dcol = lane * 4;
    #pragma unroll 2
    for (int j4 = 0; j4 < NN / 4; ++j4) {
        float alr[5][4];
        #pragma unroll
        for (int r = 0; r < 5; ++r) {
            const float4 a4 = *(const float4*)&sS[wv * 5 + r][4 * j4]; // b128 bcast
            alr[r][0] = a4.x; alr[r][1] = a4.y; alr[r][2] = a4.z; alr[r][3] = a4.w;
        }
        #pragma unroll
        for (int q = 0; q < 4; ++q) {
            const float4 hv = *(const float4*)(hb + (size_t)(4 * j4 + q) * ND + dcol);
            #pragma unroll
            for (int r = 0; r < 5; ++r) {
                o[r][0] += alr[r][q] * hv.x;
                o[r][1] += alr[r][q] * hv.y;
                o[r][2] += alr[r][q] * hv.z;
                o[r][3] += alr[r][q] * hv.w;
            }
        }
    }

    #pragma unroll
    for (int r = 0; r < 5; ++r) {
        const int i = i0 + wv * 5 + r;
        float4 v;
        v.x = o[r][0]; v.y = o[r][1]; v.z = o[r][2]; v.w = o[r][3];
        *(float4*)(out + ((size_t)b * NN + i) * ND + dcol) = v;
    }
}

extern "C" void kernel_launch(void* const* d_in, const int* in_sizes, int n_in,
                              void* d_out, int out_size, void* d_ws, size_t ws_size,
                              hipStream_t stream) {
    const float* h   = (const float*)d_in[0];
    const int*   adj = (const int*)d_in[1];
    const float* a0  = (const float*)d_in[2];
    const float* a1  = (const float*)d_in[3];
    const float* a2  = (const float*)d_in[4];
    const float* a3  = (const float*)d_in[5];
    float* out = (float*)d_out;

    dim3 grid(NB * NTILE);   // 2560 blocks
    dim3 block(512);
    gat_fused_w2_kernel<<<grid, block, 0, stream>>>(h, adj, a0, a1, a2, a3, out);
}